// Round 1
// baseline (276.482 us; speedup 1.0000x reference)
//
#include <hip/hip_runtime.h>
#include <hip/hip_bf16.h>

typedef __bf16 bf16x8 __attribute__((ext_vector_type(8)));
typedef unsigned short u16x8 __attribute__((ext_vector_type(8)));
typedef float f32x4 __attribute__((ext_vector_type(4)));

#define MFMA(a, b, c) __builtin_amdgcn_mfma_f32_16x16x32_bf16(a, b, c, 0, 0, 0)

#define LQ 2048
#define DD 256

static __device__ __forceinline__ float bf2f(unsigned short u) {
  union { unsigned int i; float f; } x; x.i = ((unsigned int)u) << 16; return x.f;
}
static __device__ __forceinline__ unsigned short f2bf(float f) {
  union { float f; unsigned int i; } x; x.f = f;
  unsigned int r = x.i + 0x7fffu + ((x.i >> 16) & 1u);  // RNE
  return (unsigned short)(r >> 16);
}

// ---------- weight transpose: W f32 [K][N] -> WT bf16 [N][K] ----------
__global__ void wt_kernel(const float* __restrict__ W, unsigned short* __restrict__ WT,
                          int logK, int N) {
  int K = 1 << logK;
  int id = blockIdx.x * 256 + threadIdx.x;
  if (id >= K * N) return;
  int n = id >> logK;
  int k = id & (K - 1);
  WT[id] = f2bf(W[(long)k * N + n]);
}

// ---------- projection GEMM: out bf16[M][256] = A f32[M][Kd] @ W (+bias) ----------
// W supplied as WT bf16 [256][Kd]. Optionally also writes outT bf16 [b][256][2048].
__global__ __launch_bounds__(256) void proj_kernel(
    const float* __restrict__ A, const unsigned short* __restrict__ WT,
    const float* __restrict__ bias, unsigned short* __restrict__ outb,
    unsigned short* __restrict__ outT, int Kd) {
  __shared__ unsigned short A_s[128 * 32];
  __shared__ unsigned short B_s[128 * 32];
  const int tid = threadIdx.x;
  const int w = tid >> 6, lane = tid & 63, g = lane >> 4, c = lane & 15;
  const int m0 = (blockIdx.x >> 1) * 128, n0 = (blockIdx.x & 1) * 128;
  const int wr = (w >> 1) * 64, wc = (w & 1) * 64;

  f32x4 acc[4][4];
  const f32x4 z4 = {0.f, 0.f, 0.f, 0.f};
  for (int i = 0; i < 4; i++)
    for (int j = 0; j < 4; j++) acc[i][j] = z4;

  const int row_st = tid >> 1, k0 = (tid & 1) * 16;
  const unsigned swz_w = (unsigned)((row_st & 7) << 4);
  const int nk = Kd >> 5;
  for (int ks = 0; ks < nk; ks++) {
    // stage A tile (f32 -> bf16), 128 rows x 32 k
    {
      const float* src = A + (long)(m0 + row_st) * Kd + ks * 32 + k0;
      u16x8 t0, t1;
      for (int j = 0; j < 8; j++) t0[j] = f2bf(src[j]);
      for (int j = 0; j < 8; j++) t1[j] = f2bf(src[8 + j]);
      *(u16x8*)((char*)A_s + (((unsigned)(row_st * 64 + k0 * 2)) ^ swz_w)) = t0;
      *(u16x8*)((char*)A_s + (((unsigned)(row_st * 64 + k0 * 2 + 16)) ^ swz_w)) = t1;
      // stage B tile (already bf16), 128 cols x 32 k
      const unsigned short* srcB = WT + (long)(n0 + row_st) * Kd + ks * 32 + k0;
      u16x8 b0 = *(const u16x8*)srcB;
      u16x8 b1 = *(const u16x8*)(srcB + 8);
      *(u16x8*)((char*)B_s + (((unsigned)(row_st * 64 + k0 * 2)) ^ swz_w)) = b0;
      *(u16x8*)((char*)B_s + (((unsigned)(row_st * 64 + k0 * 2 + 16)) ^ swz_w)) = b1;
    }
    __syncthreads();
    bf16x8 af[4], bfr[4];
    for (int rf = 0; rf < 4; rf++) {
      int row = wr + rf * 16 + c;
      af[rf] = *(const bf16x8*)((char*)A_s +
                (((unsigned)(row * 64 + g * 16)) ^ ((row & 7) << 4)));
    }
    for (int cf = 0; cf < 4; cf++) {
      int row = wc + cf * 16 + c;
      bfr[cf] = *(const bf16x8*)((char*)B_s +
                (((unsigned)(row * 64 + g * 16)) ^ ((row & 7) << 4)));
    }
    for (int rf = 0; rf < 4; rf++)
      for (int cf = 0; cf < 4; cf++)
        acc[rf][cf] = MFMA(af[rf], bfr[cf], acc[rf][cf]);
    __syncthreads();
  }
  // epilogue: bias add, bf16 store (+ optional transposed store)
  for (int cf = 0; cf < 4; cf++) {
    const int col = n0 + wc + cf * 16 + c;
    const float bv = bias[col];
    for (int rf = 0; rf < 4; rf++) {
      const int row0 = m0 + wr + rf * 16 + g * 4;
      unsigned short pk[4];
      for (int i = 0; i < 4; i++) {
        float v = acc[rf][cf][i] + bv;
        pk[i] = f2bf(v);
        outb[(long)(row0 + i) * 256 + col] = pk[i];
      }
      if (outT) {
        const int b = row0 >> 11;       // row0 / 2048
        const int key0 = row0 & 2047;
        unsigned long long packed = (unsigned long long)pk[0] |
                                    ((unsigned long long)pk[1] << 16) |
                                    ((unsigned long long)pk[2] << 32) |
                                    ((unsigned long long)pk[3] << 48);
        *(unsigned long long*)(outT + ((long)(b * 256 + col) * LQ + key0)) = packed;
      }
    }
  }
}

// ---------- fused flash attention + residual ----------
// Q,K bf16 [B*L][256]; KT bf16 [B][256][L]; out f32 [B*L][256]
__global__ __launch_bounds__(256) void attn_kernel(
    const unsigned short* __restrict__ Qb, const unsigned short* __restrict__ Kb,
    const unsigned short* __restrict__ KTb, float* __restrict__ out) {
  __shared__ unsigned short K_s[32 * 256];   // 16KB, swizzled [key][d]
  __shared__ unsigned short KT_s[256 * 32];  // 16KB, swizzled [d][key]
  __shared__ unsigned short P_s[4][16 * 32]; // 1KB per wave, swizzled [q][key]
  const int tid = threadIdx.x;
  const int w = tid >> 6, lane = tid & 63, g = lane >> 4, c = lane & 15;
  const int b = blockIdx.x >> 5;
  const int q0 = (blockIdx.x & 31) * 64 + w * 16;
  const long qrow_base = (long)b * LQ + q0;
  const float CS = 0.03125f * 1.4426950408889634f;  // SCALE * log2(e)

  // Q fragments for this wave's 16 rows (A-operand layout)
  bf16x8 qa[8];
  {
    const unsigned short* qr = Qb + (qrow_base + c) * DD + g * 8;
    for (int ks = 0; ks < 8; ks++) qa[ks] = *(const bf16x8*)(qr + ks * 32);
  }
  f32x4 o[16];
  const f32x4 z4 = {0.f, 0.f, 0.f, 0.f};
  for (int f = 0; f < 16; f++) o[f] = z4;
  float m_[4] = {-1e30f, -1e30f, -1e30f, -1e30f};
  float l_[4] = {0.f, 0.f, 0.f, 0.f};

  const unsigned short* Kbase = Kb + (long)b * LQ * DD;
  const unsigned short* KTbase = KTb + (long)b * DD * LQ;

  const int skey = tid >> 3, sd0 = (tid & 7) * 32;  // K_s staging
  const int sk0 = (tid & 3) * 8, sdq = tid >> 2;    // KT_s staging

  for (int kt = 0; kt < 64; kt++) {
    // ---- stage K tile (32 keys) in both layouts ----
    {
      const unsigned short* src = Kbase + (long)(kt * 32 + skey) * DD + sd0;
      const unsigned sw = (unsigned)((skey & 7) << 4);
      for (int j = 0; j < 4; j++) {
        u16x8 v = *(const u16x8*)(src + j * 8);
        *(u16x8*)((char*)K_s + (((unsigned)(skey * 512 + sd0 * 2 + j * 16)) ^ sw)) = v;
      }
      for (int j = 0; j < 4; j++) {
        int d = j * 64 + sdq;
        u16x8 v = *(const u16x8*)(KTbase + (long)d * LQ + kt * 32 + sk0);
        *(u16x8*)((char*)KT_s + (((unsigned)(d * 64 + sk0 * 2)) ^ ((d & 7) << 4))) = v;
      }
    }
    __syncthreads();

    // ---- S = Q K^T (raw scores, scale folded into exp) ----
    f32x4 s0 = z4, s1 = z4;
    for (int ks = 0; ks < 8; ks++) {
      int key0 = c, key1 = 16 + c;
      bf16x8 kb0 = *(const bf16x8*)((char*)K_s +
                   (((unsigned)(key0 * 512 + ks * 64 + g * 16)) ^ ((key0 & 7) << 4)));
      bf16x8 kb1 = *(const bf16x8*)((char*)K_s +
                   (((unsigned)(key1 * 512 + ks * 64 + g * 16)) ^ ((key1 & 7) << 4)));
      s0 = MFMA(qa[ks], kb0, s0);
      s1 = MFMA(qa[ks], kb1, s1);
    }

    // ---- online softmax ----
    float m2[4];
    for (int i = 0; i < 4; i++) m2[i] = fmaxf(s0[i], s1[i]);
    for (int msk = 1; msk <= 8; msk <<= 1)
      for (int i = 0; i < 4; i++) m2[i] = fmaxf(m2[i], __shfl_xor(m2[i], msk, 64));
    bool grew = (m2[0] > m_[0]) | (m2[1] > m_[1]) | (m2[2] > m_[2]) | (m2[3] > m_[3]);
    if (__any(grew)) {  // rescale only when a row max actually grows
      for (int i = 0; i < 4; i++) {
        float mn = fmaxf(m_[i], m2[i]);
        float al = exp2f((m_[i] - mn) * CS);
        m_[i] = mn;
        l_[i] *= al;
        for (int f = 0; f < 16; f++) o[f][i] *= al;
      }
    }
    for (int i = 0; i < 4; i++) {
      int row = g * 4 + i;
      unsigned sw = (unsigned)((row & 7) << 4);
      float p0 = exp2f((s0[i] - m_[i]) * CS);
      float p1 = exp2f((s1[i] - m_[i]) * CS);
      l_[i] += p0 + p1;
      *(unsigned short*)((char*)P_s[w] + (((unsigned)(row * 64 + c * 2)) ^ sw)) = f2bf(p0);
      *(unsigned short*)((char*)P_s[w] + (((unsigned)(row * 64 + 32 + c * 2)) ^ sw)) = f2bf(p1);
    }
    asm volatile("" ::: "memory");  // order P_s writes before reads (same wave, DS in-order)

    // ---- O += P @ K (K reused as V) ----
    bf16x8 pa = *(const bf16x8*)((char*)P_s[w] +
                (((unsigned)(c * 64 + g * 16)) ^ ((c & 7) << 4)));
    for (int f = 0; f < 16; f++) {
      int d = f * 16 + c;
      bf16x8 vb = *(const bf16x8*)((char*)KT_s +
                  (((unsigned)(d * 64 + g * 16)) ^ ((d & 7) << 4)));
      o[f] = MFMA(pa, vb, o[f]);
    }
    __syncthreads();
  }

  // ---- finalize: row-sum across the 16 key-columns, divide, residual ----
  for (int msk = 1; msk <= 8; msk <<= 1)
    for (int i = 0; i < 4; i++) l_[i] += __shfl_xor(l_[i], msk, 64);
  for (int f = 0; f < 16; f++) {
    for (int i = 0; i < 4; i++) {
      long ga = (qrow_base + g * 4 + i) * DD + f * 16 + c;
      out[ga] = o[f][i] / l_[i] + bf2f(Qb[ga]);
    }
  }
}

extern "C" void kernel_launch(void* const* d_in, const int* in_sizes, int n_in,
                              void* d_out, int out_size, void* d_ws, size_t ws_size,
                              hipStream_t stream) {
  (void)in_sizes; (void)n_in; (void)out_size; (void)ws_size;
  const float* data1 = (const float*)d_in[0];  // [8,2048,1024]
  const float* data2 = (const float*)d_in[1];  // [8,2048,256]
  const float* Wq = (const float*)d_in[2];     // [1024,256]
  const float* bq = (const float*)d_in[3];     // [256]
  const float* Wk = (const float*)d_in[4];     // [256,256]
  const float* bk = (const float*)d_in[5];     // [256]
  float* out = (float*)d_out;                  // [8,2048,256] f32

  char* ws = (char*)d_ws;
  unsigned short* Qb  = (unsigned short*)(ws);                       // 8 MB
  unsigned short* Kb  = (unsigned short*)(ws + (8ull << 20));        // 8 MB
  unsigned short* KTb = (unsigned short*)(ws + (16ull << 20));       // 8 MB
  unsigned short* WqT = (unsigned short*)(ws + (24ull << 20));       // 512 KB
  unsigned short* WkT = (unsigned short*)(ws + (24ull << 20) + (512u << 10));  // 128 KB

  wt_kernel<<<dim3(1024), dim3(256), 0, stream>>>(Wq, WqT, 10, 256);
  wt_kernel<<<dim3(256), dim3(256), 0, stream>>>(Wk, WkT, 8, 256);
  proj_kernel<<<dim3(256), dim3(256), 0, stream>>>(data1, WqT, bq, Qb,
                                                   (unsigned short*)nullptr, 1024);
  proj_kernel<<<dim3(256), dim3(256), 0, stream>>>(data2, WkT, bk, Kb, KTb, 256);
  attn_kernel<<<dim3(256), dim3(256), 0, stream>>>(Qb, Kb, KTb, out);
}

// Round 3
// 242.694 us; speedup vs baseline: 1.1392x; 1.1392x over previous
//
#include <hip/hip_runtime.h>
#include <hip/hip_bf16.h>

typedef __bf16 bf16x8 __attribute__((ext_vector_type(8)));
typedef unsigned short u16x8 __attribute__((ext_vector_type(8)));
typedef unsigned short u16x4 __attribute__((ext_vector_type(4)));
typedef float f32x4 __attribute__((ext_vector_type(4)));

#define MFMA(a, b, c) __builtin_amdgcn_mfma_f32_16x16x32_bf16(a, b, c, 0, 0, 0)

#define LQ 2048
#define DD 256

static __device__ __forceinline__ float bf2f(unsigned short u) {
  union { unsigned int i; float f; } x; x.i = ((unsigned int)u) << 16; return x.f;
}
static __device__ __forceinline__ unsigned short f2bf(float f) {
  union { float f; unsigned int i; } x; x.f = f;
  unsigned int r = x.i + 0x7fffu + ((x.i >> 16) & 1u);  // RNE
  return (unsigned short)(r >> 16);
}

// ---------- weight transpose: W f32 [K][N] -> WT bf16 [N][K] ----------
__global__ void wt_kernel(const float* __restrict__ W, unsigned short* __restrict__ WT,
                          int logK, int N) {
  int K = 1 << logK;
  int id = blockIdx.x * 256 + threadIdx.x;
  if (id >= K * N) return;
  int n = id >> logK;
  int k = id & (K - 1);
  WT[id] = f2bf(W[(long)k * N + n]);
}

// ---------- projection GEMM: out bf16[M][256] = A f32[M][Kd] @ W (+bias) ----------
__global__ __launch_bounds__(256) void proj_kernel(
    const float* __restrict__ A, const unsigned short* __restrict__ WT,
    const float* __restrict__ bias, unsigned short* __restrict__ outb,
    unsigned short* __restrict__ outT, int Kd) {
  __shared__ unsigned short A_s[128 * 32];
  __shared__ unsigned short B_s[128 * 32];
  const int tid = threadIdx.x;
  const int w = tid >> 6, lane = tid & 63, g = lane >> 4, c = lane & 15;
  const int m0 = (blockIdx.x >> 1) * 128, n0 = (blockIdx.x & 1) * 128;
  const int wr = (w >> 1) * 64, wc = (w & 1) * 64;

  f32x4 acc[4][4];
  const f32x4 z4 = {0.f, 0.f, 0.f, 0.f};
  for (int i = 0; i < 4; i++)
    for (int j = 0; j < 4; j++) acc[i][j] = z4;

  const int row_st = tid >> 1, k0 = (tid & 1) * 16;
  const unsigned swz_w = (unsigned)((row_st & 7) << 4);
  const int nk = Kd >> 5;
  for (int ks = 0; ks < nk; ks++) {
    {
      const float* src = A + (long)(m0 + row_st) * Kd + ks * 32 + k0;
      u16x8 t0, t1;
      for (int j = 0; j < 8; j++) t0[j] = f2bf(src[j]);
      for (int j = 0; j < 8; j++) t1[j] = f2bf(src[8 + j]);
      *(u16x8*)((char*)A_s + (((unsigned)(row_st * 64 + k0 * 2)) ^ swz_w)) = t0;
      *(u16x8*)((char*)A_s + (((unsigned)(row_st * 64 + k0 * 2 + 16)) ^ swz_w)) = t1;
      const unsigned short* srcB = WT + (long)(n0 + row_st) * Kd + ks * 32 + k0;
      u16x8 b0 = *(const u16x8*)srcB;
      u16x8 b1 = *(const u16x8*)(srcB + 8);
      *(u16x8*)((char*)B_s + (((unsigned)(row_st * 64 + k0 * 2)) ^ swz_w)) = b0;
      *(u16x8*)((char*)B_s + (((unsigned)(row_st * 64 + k0 * 2 + 16)) ^ swz_w)) = b1;
    }
    __syncthreads();
    bf16x8 af[4], bfr[4];
    for (int rf = 0; rf < 4; rf++) {
      int row = wr + rf * 16 + c;
      af[rf] = *(const bf16x8*)((char*)A_s +
                (((unsigned)(row * 64 + g * 16)) ^ ((row & 7) << 4)));
    }
    for (int cf = 0; cf < 4; cf++) {
      int row = wc + cf * 16 + c;
      bfr[cf] = *(const bf16x8*)((char*)B_s +
                (((unsigned)(row * 64 + g * 16)) ^ ((row & 7) << 4)));
    }
    for (int rf = 0; rf < 4; rf++)
      for (int cf = 0; cf < 4; cf++)
        acc[rf][cf] = MFMA(af[rf], bfr[cf], acc[rf][cf]);
    __syncthreads();
  }
  for (int cf = 0; cf < 4; cf++) {
    const int col = n0 + wc + cf * 16 + c;
    const float bv = bias[col];
    for (int rf = 0; rf < 4; rf++) {
      const int row0 = m0 + wr + rf * 16 + g * 4;
      unsigned short pk[4];
      for (int i = 0; i < 4; i++) {
        float v = acc[rf][cf][i] + bv;
        pk[i] = f2bf(v);
        outb[(long)(row0 + i) * 256 + col] = pk[i];
      }
      if (outT) {
        const int b = row0 >> 11;
        const int key0 = row0 & 2047;
        unsigned long long packed = (unsigned long long)pk[0] |
                                    ((unsigned long long)pk[1] << 16) |
                                    ((unsigned long long)pk[2] << 32) |
                                    ((unsigned long long)pk[3] << 48);
        *(unsigned long long*)(outT + ((long)(b * 256 + col) * LQ + key0)) = packed;
      }
    }
  }
}

// ---------- fused flash attention + residual (barrier-free main loop) ----------
// Block: 256 thr = 4 waves, all on the SAME 32 q-rows; wave w owns keys
// [w*512,(w+1)*512). B-fragments load directly from global (L2-resident K/KT).
// End: 4-way (m,l,o) merge via LDS, then residual add + store.
__global__ __launch_bounds__(256, 2) void attn_kernel(
    const unsigned short* __restrict__ Qb, const unsigned short* __restrict__ Kb,
    const unsigned short* __restrict__ KTb, float* __restrict__ out) {
  __shared__ unsigned short P_s[4][32 * 32];  // 8KB, per-wave swizzled [row][key]
  __shared__ float obuf[32 * 256];            // 32KB, swizzled merge buffer
  __shared__ float ml_s[2][4][32];            // [m|l][wave][row]
  const int tid = threadIdx.x;
  const int w = tid >> 6, lane = tid & 63, g = lane >> 4, c = lane & 15;
  const int lid = (blockIdx.x & 7) * 64 + (blockIdx.x >> 3);  // XCD-chunked
  const int b = lid >> 6;
  const int q0 = (lid & 63) * 32;
  const long qrow_base = (long)b * LQ + q0;
  const float CS = 0.03125f * 1.4426950408889634f;  // SCALE * log2(e)

  const unsigned short* Kbase = Kb + (long)b * LQ * DD;
  const unsigned short* KTbase = KTb + (long)b * DD * LQ;

  // Q A-fragments: 2 row-frags x 8 k-steps (persistent, 64 VGPR)
  bf16x8 qa[2][8];
#pragma unroll
  for (int r = 0; r < 2; r++) {
    const unsigned short* qr = Qb + (qrow_base + r * 16 + c) * DD + g * 8;
#pragma unroll
    for (int ks = 0; ks < 8; ks++) qa[r][ks] = *(const bf16x8*)(qr + ks * 32);
  }

  f32x4 o[2][16];
  const f32x4 z4 = {0.f, 0.f, 0.f, 0.f};
#pragma unroll
  for (int r = 0; r < 2; r++)
#pragma unroll
    for (int f = 0; f < 16; f++) o[r][f] = z4;
  float m_[2][4], l_[2][4];
#pragma unroll
  for (int r = 0; r < 2; r++)
#pragma unroll
    for (int i = 0; i < 4; i++) { m_[r][i] = -1e30f; l_[r][i] = 0.f; }

  const int kw0 = w * 512;
  for (int kt = 0; kt < 16; kt++) {
    const int k0 = kw0 + kt * 32;
    // ---- S = Q K^T : B-frags straight from global (L2) ----
    f32x4 s[2][2];
    s[0][0] = z4; s[0][1] = z4; s[1][0] = z4; s[1][1] = z4;
#pragma unroll
    for (int ks = 0; ks < 8; ks++) {
      const unsigned short* kp = Kbase + (long)(k0 + c) * DD + ks * 32 + g * 8;
      bf16x8 kb0 = *(const bf16x8*)(kp);
      bf16x8 kb1 = *(const bf16x8*)(kp + 16 * DD);
      s[0][0] = MFMA(qa[0][ks], kb0, s[0][0]);
      s[0][1] = MFMA(qa[0][ks], kb1, s[0][1]);
      s[1][0] = MFMA(qa[1][ks], kb0, s[1][0]);
      s[1][1] = MFMA(qa[1][ks], kb1, s[1][1]);
    }
    // ---- online softmax (rows live in (g,i); reduce over c via shfl) ----
    float m2[2][4];
#pragma unroll
    for (int r = 0; r < 2; r++)
#pragma unroll
      for (int i = 0; i < 4; i++) m2[r][i] = fmaxf(s[r][0][i], s[r][1][i]);
#pragma unroll
    for (int msk = 1; msk <= 8; msk <<= 1)
#pragma unroll
      for (int r = 0; r < 2; r++)
#pragma unroll
        for (int i = 0; i < 4; i++) m2[r][i] = fmaxf(m2[r][i], __shfl_xor(m2[r][i], msk, 64));
    bool grew = false;
#pragma unroll
    for (int r = 0; r < 2; r++)
#pragma unroll
      for (int i = 0; i < 4; i++) grew |= (m2[r][i] > m_[r][i]);
    if (__any(grew)) {
#pragma unroll
      for (int r = 0; r < 2; r++)
#pragma unroll
        for (int i = 0; i < 4; i++) {
          float mn = fmaxf(m_[r][i], m2[r][i]);
          float al = exp2f((m_[r][i] - mn) * CS);
          m_[r][i] = mn;
          l_[r][i] *= al;
#pragma unroll
          for (int f = 0; f < 16; f++) o[r][f][i] *= al;
        }
    }
    // ---- P -> LDS (swizzled), read back as A-frags ----
#pragma unroll
    for (int r = 0; r < 2; r++)
#pragma unroll
      for (int i = 0; i < 4; i++) {
        const int row = r * 16 + 4 * g + i;
        const unsigned swz = (unsigned)(i << 4);  // row & 3 == i
        float p0 = exp2f((s[r][0][i] - m_[r][i]) * CS);
        float p1 = exp2f((s[r][1][i] - m_[r][i]) * CS);
        l_[r][i] += p0 + p1;
        char* base = (char*)P_s[w] + row * 64;
        *(unsigned short*)(base + ((unsigned)(c * 2) ^ swz)) = f2bf(p0);
        *(unsigned short*)(base + ((unsigned)(32 + c * 2) ^ swz)) = f2bf(p1);
      }
    asm volatile("" ::: "memory");  // same-wave DS ordering
    bf16x8 pa[2];
#pragma unroll
    for (int r = 0; r < 2; r++) {
      const int row = r * 16 + c;
      pa[r] = *(const bf16x8*)((char*)P_s[w] + row * 64 +
                               ((unsigned)(g * 16) ^ ((unsigned)(c & 3) << 4)));
    }
    // ---- O += P @ V (V = K, via KT for contiguous frag loads) ----
#pragma unroll
    for (int f = 0; f < 16; f++) {
      const unsigned short* vp = KTbase + (long)(f * 16 + c) * LQ + k0 + g * 8;
      bf16x8 vb = *(const bf16x8*)vp;
      o[0][f] = MFMA(pa[0], vb, o[0][f]);
      o[1][f] = MFMA(pa[1], vb, o[1][f]);
    }
  }

  // ---- reduce l_ across the 16 key-columns (was the R2 bug: missing) ----
#pragma unroll
  for (int msk = 1; msk <= 8; msk <<= 1)
#pragma unroll
    for (int r = 0; r < 2; r++)
#pragma unroll
      for (int i = 0; i < 4; i++) l_[r][i] += __shfl_xor(l_[r][i], msk, 64);

  // ---- merge the 4 key-split partials ----
  if (c == 0) {
#pragma unroll
    for (int r = 0; r < 2; r++)
#pragma unroll
      for (int i = 0; i < 4; i++) {
        const int row = r * 16 + 4 * g + i;
        ml_s[0][w][row] = m_[r][i];
        ml_s[1][w][row] = l_[r][i];
      }
  }
  __syncthreads();
  // scale own partial by alpha_w = 2^((m_w - M)*CS)
#pragma unroll
  for (int r = 0; r < 2; r++)
#pragma unroll
    for (int i = 0; i < 4; i++) {
      const int row = r * 16 + 4 * g + i;
      float M = fmaxf(fmaxf(ml_s[0][0][row], ml_s[0][1][row]),
                      fmaxf(ml_s[0][2][row], ml_s[0][3][row]));
      float al = exp2f((m_[r][i] - M) * CS);
#pragma unroll
      for (int f = 0; f < 16; f++) o[r][f][i] *= al;
    }
  // sequential accumulate into obuf (bank-swizzled by g)
  for (int rw = 0; rw < 4; rw++) {
    if (w == rw) {
#pragma unroll
      for (int r = 0; r < 2; r++)
#pragma unroll
        for (int f = 0; f < 16; f++)
#pragma unroll
          for (int i = 0; i < 4; i++) {
            const int row = r * 16 + 4 * g + i;
            const int idx = row * 256 + ((f * 16 + c) ^ (g << 2));
            if (rw == 0) obuf[idx] = o[r][f][i];
            else obuf[idx] += o[r][f][i];
          }
    }
    __syncthreads();
  }
  // ---- finalize: divide by L, residual add, store f32 ----
  {
    const int row = tid >> 3;
    const int d0 = (tid & 7) * 32;
    float mv0 = ml_s[0][0][row], mv1 = ml_s[0][1][row];
    float mv2 = ml_s[0][2][row], mv3 = ml_s[0][3][row];
    float M = fmaxf(fmaxf(mv0, mv1), fmaxf(mv2, mv3));
    float L = exp2f((mv0 - M) * CS) * ml_s[1][0][row] +
              exp2f((mv1 - M) * CS) * ml_s[1][1][row] +
              exp2f((mv2 - M) * CS) * ml_s[1][2][row] +
              exp2f((mv3 - M) * CS) * ml_s[1][3][row];
    const float invL = 1.0f / L;
    const int gr = (row >> 2) & 3;
    const long orow = (qrow_base + row) * (long)DD;
#pragma unroll
    for (int j = 0; j < 8; j++) {
      const int d = d0 + j * 4;
      f32x4 v = *(const f32x4*)&obuf[row * 256 + (d ^ (gr << 2))];
      u16x4 q = *(const u16x4*)(Qb + orow + d);
      f32x4 rres;
#pragma unroll
      for (int e = 0; e < 4; e++) rres[e] = v[e] * invL + bf2f(q[e]);
      *(f32x4*)(out + orow + d) = rres;
    }
  }
}

extern "C" void kernel_launch(void* const* d_in, const int* in_sizes, int n_in,
                              void* d_out, int out_size, void* d_ws, size_t ws_size,
                              hipStream_t stream) {
  (void)in_sizes; (void)n_in; (void)out_size; (void)ws_size;
  const float* data1 = (const float*)d_in[0];  // [8,2048,1024]
  const float* data2 = (const float*)d_in[1];  // [8,2048,256]
  const float* Wq = (const float*)d_in[2];     // [1024,256]
  const float* bq = (const float*)d_in[3];     // [256]
  const float* Wk = (const float*)d_in[4];     // [256,256]
  const float* bk = (const float*)d_in[5];     // [256]
  float* out = (float*)d_out;                  // [8,2048,256] f32

  char* ws = (char*)d_ws;
  unsigned short* Qb  = (unsigned short*)(ws);                       // 8 MB
  unsigned short* Kb  = (unsigned short*)(ws + (8ull << 20));        // 8 MB
  unsigned short* KTb = (unsigned short*)(ws + (16ull << 20));       // 8 MB
  unsigned short* WqT = (unsigned short*)(ws + (24ull << 20));       // 512 KB
  unsigned short* WkT = (unsigned short*)(ws + (24ull << 20) + (512u << 10));  // 128 KB

  wt_kernel<<<dim3(1024), dim3(256), 0, stream>>>(Wq, WqT, 10, 256);
  wt_kernel<<<dim3(256), dim3(256), 0, stream>>>(Wk, WkT, 8, 256);
  proj_kernel<<<dim3(256), dim3(256), 0, stream>>>(data1, WqT, bq, Qb,
                                                   (unsigned short*)nullptr, 1024);
  proj_kernel<<<dim3(256), dim3(256), 0, stream>>>(data2, WkT, bk, Kb, KTb, 256);
  attn_kernel<<<dim3(512), dim3(256), 0, stream>>>(Qb, Kb, KTb, out);
}

// Round 4
// 151.354 us; speedup vs baseline: 1.8267x; 1.6035x over previous
//
#include <hip/hip_runtime.h>
#include <hip/hip_bf16.h>

typedef __bf16 bf16x8 __attribute__((ext_vector_type(8)));
typedef unsigned short u16x8 __attribute__((ext_vector_type(8)));
typedef unsigned short u16x4 __attribute__((ext_vector_type(4)));
typedef float f32x4 __attribute__((ext_vector_type(4)));

#define MFMA(a, b, c) __builtin_amdgcn_mfma_f32_16x16x32_bf16(a, b, c, 0, 0, 0)

#define LQ 2048
#define DD 256

static __device__ __forceinline__ float bf2f(unsigned short u) {
  union { unsigned int i; float f; } x; x.i = ((unsigned int)u) << 16; return x.f;
}
static __device__ __forceinline__ unsigned short f2bf(float f) {
  union { float f; unsigned int i; } x; x.f = f;
  unsigned int r = x.i + 0x7fffu + ((x.i >> 16) & 1u);  // RNE
  return (unsigned short)(r >> 16);
}
static __device__ __forceinline__ void gll16(const void* g, void* l) {
  __builtin_amdgcn_global_load_lds(
      (const __attribute__((address_space(1))) unsigned int*)g,
      (__attribute__((address_space(3))) unsigned int*)l, 16, 0, 0);
}

// ---------- weight transpose: W f32 [K][N] -> WT bf16 [N][K] ----------
__global__ void wt_kernel(const float* __restrict__ W, unsigned short* __restrict__ WT,
                          int logK, int N) {
  int K = 1 << logK;
  int id = blockIdx.x * 256 + threadIdx.x;
  if (id >= K * N) return;
  int n = id >> logK;
  int k = id & (K - 1);
  WT[id] = f2bf(W[(long)k * N + n]);
}

// ---------- projection GEMM: out bf16[M][256] = A f32[M][Kd] @ W (+bias) ----------
__global__ __launch_bounds__(256) void proj_kernel(
    const float* __restrict__ A, const unsigned short* __restrict__ WT,
    const float* __restrict__ bias, unsigned short* __restrict__ outb,
    unsigned short* __restrict__ outT, int Kd) {
  __shared__ unsigned short A_s[128 * 32];
  __shared__ unsigned short B_s[128 * 32];
  const int tid = threadIdx.x;
  const int w = tid >> 6, lane = tid & 63, g = lane >> 4, c = lane & 15;
  const int m0 = (blockIdx.x >> 1) * 128, n0 = (blockIdx.x & 1) * 128;
  const int wr = (w >> 1) * 64, wc = (w & 1) * 64;

  f32x4 acc[4][4];
  const f32x4 z4 = {0.f, 0.f, 0.f, 0.f};
  for (int i = 0; i < 4; i++)
    for (int j = 0; j < 4; j++) acc[i][j] = z4;

  const int row_st = tid >> 1, k0 = (tid & 1) * 16;
  const unsigned swz_w = (unsigned)((row_st & 7) << 4);
  const int nk = Kd >> 5;
  for (int ks = 0; ks < nk; ks++) {
    {
      const float* src = A + (long)(m0 + row_st) * Kd + ks * 32 + k0;
      u16x8 t0, t1;
      for (int j = 0; j < 8; j++) t0[j] = f2bf(src[j]);
      for (int j = 0; j < 8; j++) t1[j] = f2bf(src[8 + j]);
      *(u16x8*)((char*)A_s + (((unsigned)(row_st * 64 + k0 * 2)) ^ swz_w)) = t0;
      *(u16x8*)((char*)A_s + (((unsigned)(row_st * 64 + k0 * 2 + 16)) ^ swz_w)) = t1;
      const unsigned short* srcB = WT + (long)(n0 + row_st) * Kd + ks * 32 + k0;
      u16x8 b0 = *(const u16x8*)srcB;
      u16x8 b1 = *(const u16x8*)(srcB + 8);
      *(u16x8*)((char*)B_s + (((unsigned)(row_st * 64 + k0 * 2)) ^ swz_w)) = b0;
      *(u16x8*)((char*)B_s + (((unsigned)(row_st * 64 + k0 * 2 + 16)) ^ swz_w)) = b1;
    }
    __syncthreads();
    bf16x8 af[4], bfr[4];
    for (int rf = 0; rf < 4; rf++) {
      int row = wr + rf * 16 + c;
      af[rf] = *(const bf16x8*)((char*)A_s +
                (((unsigned)(row * 64 + g * 16)) ^ ((row & 7) << 4)));
    }
    for (int cf = 0; cf < 4; cf++) {
      int row = wc + cf * 16 + c;
      bfr[cf] = *(const bf16x8*)((char*)B_s +
                (((unsigned)(row * 64 + g * 16)) ^ ((row & 7) << 4)));
    }
    for (int rf = 0; rf < 4; rf++)
      for (int cf = 0; cf < 4; cf++)
        acc[rf][cf] = MFMA(af[rf], bfr[cf], acc[rf][cf]);
    __syncthreads();
  }
  for (int cf = 0; cf < 4; cf++) {
    const int col = n0 + wc + cf * 16 + c;
    const float bv = bias[col];
    for (int rf = 0; rf < 4; rf++) {
      const int row0 = m0 + wr + rf * 16 + g * 4;
      unsigned short pk[4];
      for (int i = 0; i < 4; i++) {
        float v = acc[rf][cf][i] + bv;
        pk[i] = f2bf(v);
        outb[(long)(row0 + i) * 256 + col] = pk[i];
      }
      if (outT) {
        const int b = row0 >> 11;
        const int key0 = row0 & 2047;
        unsigned long long packed = (unsigned long long)pk[0] |
                                    ((unsigned long long)pk[1] << 16) |
                                    ((unsigned long long)pk[2] << 32) |
                                    ((unsigned long long)pk[3] << 48);
        *(unsigned long long*)(outT + ((long)(b * 256 + col) * LQ + key0)) = packed;
      }
    }
  }
}

// ---------- flash attention, LDS-staged K/V, 2-way key split across blocks ----
// Block: 4 waves x 16 q-rows = 64 rows; keys [ksplit*1024, +1024), 32-key tiles.
// K_s[key][d] and KT_s[d][key] staged via global_load_lds (async DMA), dbuf.
// ksplit==1 writes f32 partial at final location in `out`; ksplit==0 writes
// bf16 partial to Op0. m/l per row to ML. merge_kernel combines.
__global__ __launch_bounds__(256, 2) void attn_kernel(
    const unsigned short* __restrict__ Qb, const unsigned short* __restrict__ Kb,
    const unsigned short* __restrict__ KTb, unsigned short* __restrict__ Op0,
    float* __restrict__ out, float* __restrict__ ML) {
  __shared__ char Ks[2][16384];   // 32 keys x 512B (swizzled cols)
  __shared__ char KTs[2][16384];  // 256 d x 64B (swizzled cols)
  __shared__ char Ps[4][1024];    // per-wave 16 rows x 64B
  const int tid = threadIdx.x;
  const int w = tid >> 6, lane = tid & 63, g = lane >> 4, c = lane & 15;
  const int lid = ((blockIdx.x & 7) << 6) + (blockIdx.x >> 3);  // XCD-chunked
  const int ksplit = lid & 1, qg = lid >> 1;   // qg 0..255
  const int b = qg >> 5;
  const long qrow0 = (long)qg * 64;            // global row base of block
  const int kbase = ksplit * 1024;
  const float CS = 0.03125f * 1.4426950408889634f;  // SCALE * log2(e)

  // Q A-fragments (16 rows for this wave)
  bf16x8 qa[8];
  {
    const unsigned short* qr = Qb + (qrow0 + w * 16 + c) * DD + g * 8;
#pragma unroll
    for (int ks = 0; ks < 8; ks++) qa[ks] = *(const bf16x8*)(qr + ks * 32);
  }
  f32x4 o[16];
  const f32x4 z4 = {0.f, 0.f, 0.f, 0.f};
#pragma unroll
  for (int f = 0; f < 16; f++) o[f] = z4;
  float m_[4] = {-1e30f, -1e30f, -1e30f, -1e30f};
  float l_[4] = {0.f, 0.f, 0.f, 0.f};

  const char* kb_b = (const char*)(Kb + (long)b * LQ * DD);    // batch K rows
  const char* kt_b = (const char*)(KTb + (long)b * DD * LQ);   // batch KT rows

#define STAGE(buf, kt_)                                                        \
  {                                                                            \
    const int k0_ = kbase + (kt_) * 32;                                        \
    _Pragma("unroll") for (int i = 0; i < 4; i++) {                            \
      const int key = ((w * 4 + i) << 1) + (lane >> 5);                        \
      const unsigned col = ((unsigned)((lane & 31) * 16)) ^                    \
                           ((unsigned)((key & 7) << 4));                       \
      gll16(kb_b + (long)(k0_ + key) * 512 + col, &Ks[buf][(w * 4 + i) * 1024]); \
    }                                                                          \
    _Pragma("unroll") for (int i = 0; i < 4; i++) {                            \
      const int d = (w * 4 + i) * 16 + (lane >> 2);                            \
      const unsigned col = ((unsigned)((lane & 3) * 16)) ^                     \
                           ((unsigned)((d & 3) << 4));                         \
      gll16(kt_b + (long)d * 4096 + (long)k0_ * 2 + col,                       \
            &KTs[buf][(w * 4 + i) * 1024]);                                    \
    }                                                                          \
  }

  STAGE(0, 0);
  for (int kt = 0; kt < 32; kt++) {
    const int cur = kt & 1;
    __syncthreads();                    // cur tile staged (all waves), prev reads done
    if (kt + 1 < 32) STAGE(cur ^ 1, kt + 1);   // async, flies under compute

    // ---- S = Q K^T from Ks ----
    f32x4 s0 = z4, s1 = z4;
#pragma unroll
    for (int ks = 0; ks < 8; ks++) {
      const int key0 = c, key1 = 16 + c;
      bf16x8 kb0 = *(const bf16x8*)(Ks[cur] + key0 * 512 +
                   (((unsigned)(ks * 64 + g * 16)) ^ ((key0 & 7) << 4)));
      bf16x8 kb1 = *(const bf16x8*)(Ks[cur] + key1 * 512 +
                   (((unsigned)(ks * 64 + g * 16)) ^ ((key1 & 7) << 4)));
      s0 = MFMA(qa[ks], kb0, s0);
      s1 = MFMA(qa[ks], kb1, s1);
    }
    // ---- online softmax (rows in (g,i); reduce over c via shfl) ----
    float m2[4];
#pragma unroll
    for (int i = 0; i < 4; i++) m2[i] = fmaxf(s0[i], s1[i]);
#pragma unroll
    for (int msk = 1; msk <= 8; msk <<= 1)
#pragma unroll
      for (int i = 0; i < 4; i++) m2[i] = fmaxf(m2[i], __shfl_xor(m2[i], msk, 64));
    bool grew = (m2[0] > m_[0]) | (m2[1] > m_[1]) | (m2[2] > m_[2]) | (m2[3] > m_[3]);
    if (__any(grew)) {
#pragma unroll
      for (int i = 0; i < 4; i++) {
        float mn = fmaxf(m_[i], m2[i]);
        float al = exp2f((m_[i] - mn) * CS);
        m_[i] = mn;
        l_[i] *= al;
#pragma unroll
        for (int f = 0; f < 16; f++) o[f][i] *= al;
      }
    }
    // ---- P -> LDS (swizzled), read back as A-frag ----
#pragma unroll
    for (int i = 0; i < 4; i++) {
      const int row = 4 * g + i;
      const unsigned swz = (unsigned)(i << 4);
      float p0 = exp2f((s0[i] - m_[i]) * CS);
      float p1 = exp2f((s1[i] - m_[i]) * CS);
      l_[i] += p0 + p1;
      char* base = Ps[w] + row * 64;
      *(unsigned short*)(base + ((unsigned)(c * 2) ^ swz)) = f2bf(p0);
      *(unsigned short*)(base + ((unsigned)(32 + c * 2) ^ swz)) = f2bf(p1);
    }
    asm volatile("" ::: "memory");  // same-wave DS ordering
    bf16x8 pa = *(const bf16x8*)(Ps[w] + c * 64 +
                 (((unsigned)(g * 16)) ^ ((unsigned)(c & 3) << 4)));
    // ---- O += P @ V from KTs ----
#pragma unroll
    for (int f = 0; f < 16; f++) {
      const int d = f * 16 + c;
      bf16x8 vb = *(const bf16x8*)(KTs[cur] + d * 64 +
                  (((unsigned)(g * 16)) ^ ((d & 3) << 4)));
      o[f] = MFMA(pa, vb, o[f]);
    }
  }
#undef STAGE

  // ---- reduce l_ across the 16 key-columns ----
#pragma unroll
  for (int msk = 1; msk <= 8; msk <<= 1)
#pragma unroll
    for (int i = 0; i < 4; i++) l_[i] += __shfl_xor(l_[i], msk, 64);

  // ---- write partial (no normalization; merge kernel does it) ----
  if (ksplit) {
    float* op = out + qrow0 * DD;
#pragma unroll
    for (int f = 0; f < 16; f++)
#pragma unroll
      for (int i = 0; i < 4; i++)
        op[(w * 16 + g * 4 + i) * DD + f * 16 + c] = o[f][i];
  } else {
    unsigned short* op = Op0 + qrow0 * DD;
#pragma unroll
    for (int f = 0; f < 16; f++)
#pragma unroll
      for (int i = 0; i < 4; i++)
        op[(w * 16 + g * 4 + i) * DD + f * 16 + c] = f2bf(o[f][i]);
  }
  if (c == 0) {
    float* mlp = ML + (qg * 2 + ksplit) * 128;
#pragma unroll
    for (int i = 0; i < 4; i++) {
      mlp[w * 16 + g * 4 + i] = m_[i];
      mlp[64 + w * 16 + g * 4 + i] = l_[i];
    }
  }
}

// ---------- merge the two key-split partials + residual ----------
__global__ __launch_bounds__(256) void merge_kernel(
    const unsigned short* __restrict__ Op0, const float* __restrict__ ML,
    const unsigned short* __restrict__ Qb, float* __restrict__ out) {
  const float CS = 0.03125f * 1.4426950408889634f;
  const long gid = (long)blockIdx.x * 256 + threadIdx.x;
  const long idx = gid * 8;
  const int row = (int)(idx >> 8);
  const int qg = row >> 6, qr = row & 63;
  const float m0 = ML[(qg * 2) * 128 + qr], l0 = ML[(qg * 2) * 128 + 64 + qr];
  const float m1 = ML[(qg * 2 + 1) * 128 + qr], l1 = ML[(qg * 2 + 1) * 128 + 64 + qr];
  const float M = fmaxf(m0, m1);
  const float e0 = exp2f((m0 - M) * CS), e1 = exp2f((m1 - M) * CS);
  const float inv = 1.0f / (e0 * l0 + e1 * l1);
  u16x8 p0 = *(const u16x8*)(Op0 + idx);
  f32x4 p1a = *(const f32x4*)(out + idx);
  f32x4 p1b = *(const f32x4*)(out + idx + 4);
  u16x8 qv = *(const u16x8*)(Qb + idx);
  f32x4 ra, rb;
#pragma unroll
  for (int e = 0; e < 4; e++)
    ra[e] = (e0 * bf2f(p0[e]) + e1 * p1a[e]) * inv + bf2f(qv[e]);
#pragma unroll
  for (int e = 0; e < 4; e++)
    rb[e] = (e0 * bf2f(p0[4 + e]) + e1 * p1b[e]) * inv + bf2f(qv[4 + e]);
  *(f32x4*)(out + idx) = ra;
  *(f32x4*)(out + idx + 4) = rb;
}

extern "C" void kernel_launch(void* const* d_in, const int* in_sizes, int n_in,
                              void* d_out, int out_size, void* d_ws, size_t ws_size,
                              hipStream_t stream) {
  (void)in_sizes; (void)n_in; (void)out_size; (void)ws_size;
  const float* data1 = (const float*)d_in[0];  // [8,2048,1024]
  const float* data2 = (const float*)d_in[1];  // [8,2048,256]
  const float* Wq = (const float*)d_in[2];     // [1024,256]
  const float* bq = (const float*)d_in[3];     // [256]
  const float* Wk = (const float*)d_in[4];     // [256,256]
  const float* bk = (const float*)d_in[5];     // [256]
  float* out = (float*)d_out;                  // [8,2048,256] f32

  char* ws = (char*)d_ws;
  unsigned short* Qb  = (unsigned short*)(ws);                        // 8 MB
  unsigned short* Kb  = (unsigned short*)(ws + (8ull << 20));         // 8 MB
  unsigned short* KTb = (unsigned short*)(ws + (16ull << 20));        // 8 MB
  unsigned short* WqT = (unsigned short*)(ws + (24ull << 20));        // 512 KB
  unsigned short* WkT = (unsigned short*)(ws + (24ull << 20) + (512u << 10));  // 128 KB
  unsigned short* Op0 = (unsigned short*)(ws + (25ull << 20));        // 8 MB (bf16 partial)
  float*          MLb = (float*)(ws + (33ull << 20));                 // 256 KB

  wt_kernel<<<dim3(1024), dim3(256), 0, stream>>>(Wq, WqT, 10, 256);
  wt_kernel<<<dim3(256), dim3(256), 0, stream>>>(Wk, WkT, 8, 256);
  proj_kernel<<<dim3(256), dim3(256), 0, stream>>>(data1, WqT, bq, Qb,
                                                   (unsigned short*)nullptr, 1024);
  proj_kernel<<<dim3(256), dim3(256), 0, stream>>>(data2, WkT, bk, Kb, KTb, 256);
  attn_kernel<<<dim3(512), dim3(256), 0, stream>>>(Qb, Kb, KTb, Op0, out, MLb);
  merge_kernel<<<dim3(2048), dim3(256), 0, stream>>>(Op0, MLb, Qb, out);
}

// Round 5
// 145.070 us; speedup vs baseline: 1.9058x; 1.0433x over previous
//
#include <hip/hip_runtime.h>
#include <hip/hip_bf16.h>

typedef __bf16 bf16x8 __attribute__((ext_vector_type(8)));
typedef unsigned short u16x8 __attribute__((ext_vector_type(8)));
typedef unsigned short u16x4 __attribute__((ext_vector_type(4)));
typedef float f32x4 __attribute__((ext_vector_type(4)));

#define MFMA(a, b, c) __builtin_amdgcn_mfma_f32_16x16x32_bf16(a, b, c, 0, 0, 0)

#define LQ 2048
#define DD 256

static __device__ __forceinline__ float bf2f(unsigned short u) {
  union { unsigned int i; float f; } x; x.i = ((unsigned int)u) << 16; return x.f;
}
static __device__ __forceinline__ unsigned short f2bf(float f) {
  union { float f; unsigned int i; } x; x.f = f;
  unsigned int r = x.i + 0x7fffu + ((x.i >> 16) & 1u);  // RNE
  return (unsigned short)(r >> 16);
}
static __device__ __forceinline__ void gll16(const void* g, void* l) {
  __builtin_amdgcn_global_load_lds(
      (const __attribute__((address_space(1))) unsigned int*)g,
      (__attribute__((address_space(3))) unsigned int*)l, 16, 0, 0);
}

// ---------- weight transpose: W f32 [K][N] -> WT bf16 [N][K] ----------
__global__ void wt_kernel(const float* __restrict__ W, unsigned short* __restrict__ WT,
                          int logK, int N) {
  int K = 1 << logK;
  int id = blockIdx.x * 256 + threadIdx.x;
  if (id >= K * N) return;
  int n = id >> logK;
  int k = id & (K - 1);
  WT[id] = f2bf(W[(long)k * N + n]);
}

// ---------- projection GEMM: out bf16[M][256] = A f32[M][Kd] @ W (+bias) ----------
__global__ __launch_bounds__(256) void proj_kernel(
    const float* __restrict__ A, const unsigned short* __restrict__ WT,
    const float* __restrict__ bias, unsigned short* __restrict__ outb,
    unsigned short* __restrict__ outT, int Kd) {
  __shared__ unsigned short A_s[128 * 32];
  __shared__ unsigned short B_s[128 * 32];
  const int tid = threadIdx.x;
  const int w = tid >> 6, lane = tid & 63, g = lane >> 4, c = lane & 15;
  const int m0 = (blockIdx.x >> 1) * 128, n0 = (blockIdx.x & 1) * 128;
  const int wr = (w >> 1) * 64, wc = (w & 1) * 64;

  f32x4 acc[4][4];
  const f32x4 z4 = {0.f, 0.f, 0.f, 0.f};
  for (int i = 0; i < 4; i++)
    for (int j = 0; j < 4; j++) acc[i][j] = z4;

  const int row_st = tid >> 1, k0 = (tid & 1) * 16;
  const unsigned swz_w = (unsigned)((row_st & 7) << 4);
  const int nk = Kd >> 5;
  for (int ks = 0; ks < nk; ks++) {
    {
      const float* src = A + (long)(m0 + row_st) * Kd + ks * 32 + k0;
      f32x4 a0 = *(const f32x4*)(src);
      f32x4 a1 = *(const f32x4*)(src + 4);
      f32x4 a2 = *(const f32x4*)(src + 8);
      f32x4 a3 = *(const f32x4*)(src + 12);
      bf16x8 t0, t1;
#pragma unroll
      for (int j = 0; j < 4; j++) {
        t0[j] = (__bf16)a0[j]; t0[4 + j] = (__bf16)a1[j];
        t1[j] = (__bf16)a2[j]; t1[4 + j] = (__bf16)a3[j];
      }
      *(bf16x8*)((char*)A_s + (((unsigned)(row_st * 64 + k0 * 2)) ^ swz_w)) = t0;
      *(bf16x8*)((char*)A_s + (((unsigned)(row_st * 64 + k0 * 2 + 16)) ^ swz_w)) = t1;
      const unsigned short* srcB = WT + (long)(n0 + row_st) * Kd + ks * 32 + k0;
      u16x8 b0 = *(const u16x8*)srcB;
      u16x8 b1 = *(const u16x8*)(srcB + 8);
      *(u16x8*)((char*)B_s + (((unsigned)(row_st * 64 + k0 * 2)) ^ swz_w)) = b0;
      *(u16x8*)((char*)B_s + (((unsigned)(row_st * 64 + k0 * 2 + 16)) ^ swz_w)) = b1;
    }
    __syncthreads();
    bf16x8 af[4], bfr[4];
    for (int rf = 0; rf < 4; rf++) {
      int row = wr + rf * 16 + c;
      af[rf] = *(const bf16x8*)((char*)A_s +
                (((unsigned)(row * 64 + g * 16)) ^ ((row & 7) << 4)));
    }
    for (int cf = 0; cf < 4; cf++) {
      int row = wc + cf * 16 + c;
      bfr[cf] = *(const bf16x8*)((char*)B_s +
                (((unsigned)(row * 64 + g * 16)) ^ ((row & 7) << 4)));
    }
    for (int rf = 0; rf < 4; rf++)
      for (int cf = 0; cf < 4; cf++)
        acc[rf][cf] = MFMA(af[rf], bfr[cf], acc[rf][cf]);
    __syncthreads();
  }
  for (int cf = 0; cf < 4; cf++) {
    const int col = n0 + wc + cf * 16 + c;
    const float bv = bias[col];
    for (int rf = 0; rf < 4; rf++) {
      const int row0 = m0 + wr + rf * 16 + g * 4;
      unsigned short pk[4];
      for (int i = 0; i < 4; i++) {
        float v = acc[rf][cf][i] + bv;
        pk[i] = f2bf(v);
        outb[(long)(row0 + i) * 256 + col] = pk[i];
      }
      if (outT) {
        const int b = row0 >> 11;
        const int key0 = row0 & 2047;
        unsigned long long packed = (unsigned long long)pk[0] |
                                    ((unsigned long long)pk[1] << 16) |
                                    ((unsigned long long)pk[2] << 32) |
                                    ((unsigned long long)pk[3] << 48);
        *(unsigned long long*)(outT + ((long)(b * 256 + col) * LQ + key0)) = packed;
      }
    }
  }
}

// ---------- flash attention, slot-linear LDS, 2-way key split across blocks ---
// Ks slot (ks,g,key): byte ks*2048+g*512+key*16 holds K[k0+key][ks*32+g*8 ..+8]
// KTs slot (f,g,c):   byte f*1024+g*256+c*16  holds KT[f*16+c][k0+g*8 ..+8]
// Both staged via gll16 (wave-uniform LDS base + lane*16; per-lane global src).
// QK read lane(g,c): base g*512+c*16, imm ks*2048(+256)  -> conflict-free.
// PV read lane(g,c): base g*256+c*16, imm f*1024          -> conflict-free.
__global__ __launch_bounds__(256, 2) void attn_kernel(
    const unsigned short* __restrict__ Qb, const unsigned short* __restrict__ Kb,
    const unsigned short* __restrict__ KTb, unsigned short* __restrict__ Op0,
    float* __restrict__ out, float* __restrict__ ML) {
  __shared__ char Ks[2][16384];
  __shared__ char KTs[2][16384];
  __shared__ char Ps[4][1024];
  const int tid = threadIdx.x;
  const int w = tid >> 6, lane = tid & 63, g = lane >> 4, c = lane & 15;
  const int lid = ((blockIdx.x & 7) << 6) + (blockIdx.x >> 3);  // XCD-chunked
  const int ksplit = lid & 1, qg = lid >> 1;   // qg 0..255
  const int b = qg >> 5;
  const long qrow0 = (long)qg * 64;
  const int kbase = ksplit * 1024;
  const float CS = 0.03125f * 1.4426950408889634f;  // SCALE * log2(e)
  const float THRM = 8.0f / CS;                     // defer-max threshold (raw)

  bf16x8 qa[8];
  {
    const unsigned short* qr = Qb + (qrow0 + w * 16 + c) * DD + g * 8;
#pragma unroll
    for (int ks = 0; ks < 8; ks++) qa[ks] = *(const bf16x8*)(qr + ks * 32);
  }
  f32x4 o[16];
  const f32x4 z4 = {0.f, 0.f, 0.f, 0.f};
#pragma unroll
  for (int f = 0; f < 16; f++) o[f] = z4;
  float m_[4] = {-1e30f, -1e30f, -1e30f, -1e30f};
  float l_[4] = {0.f, 0.f, 0.f, 0.f};

  const char* kb_b = (const char*)(Kb + (long)b * LQ * DD);
  const char* kt_b = (const char*)(KTb + (long)b * DD * LQ);

  // staging decompositions (uniform per wave where needed)
  const int ks_w = w >> 1;                       // Ks: ks = i*2 + (w>>1)
  const int kg_w = ((w & 1) << 1) + (lane >> 5); // Ks: g-component
  const int kkey = lane & 31;                    // Ks: key
  // KTs: f = i*4 + w, g = g, c = c

#define STAGE(buf, kt_)                                                         \
  {                                                                             \
    const int k0_ = kbase + (kt_) * 32;                                         \
    _Pragma("unroll") for (int i = 0; i < 4; i++) {                             \
      gll16(kb_b + (long)(k0_ + kkey) * 512 + (i * 2 + ks_w) * 64 + kg_w * 16,  \
            Ks[buf] + i * 4096 + w * 1024);                                     \
    }                                                                           \
    _Pragma("unroll") for (int i = 0; i < 4; i++) {                             \
      const int f_ = i * 4 + w;                                                 \
      gll16(kt_b + (long)(f_ * 16 + c) * 4096 + (long)k0_ * 2 + g * 16,         \
            KTs[buf] + f_ * 1024);                                              \
    }                                                                           \
  }

  STAGE(0, 0);
  for (int kt = 0; kt < 32; kt++) {
    const int cur = kt & 1;
    __syncthreads();
    if (kt + 1 < 32) STAGE(cur ^ 1, kt + 1);

    // ---- S = Q K^T ----
    const char* kread = Ks[cur] + g * 512 + c * 16;
    f32x4 s0 = z4, s1 = z4;
#pragma unroll
    for (int ks = 0; ks < 8; ks++) {
      bf16x8 kb0 = *(const bf16x8*)(kread + ks * 2048);
      bf16x8 kb1 = *(const bf16x8*)(kread + ks * 2048 + 256);
      s0 = MFMA(qa[ks], kb0, s0);
      s1 = MFMA(qa[ks], kb1, s1);
    }
    // ---- online softmax with defer-max (T13) ----
    float m2[4];
#pragma unroll
    for (int i = 0; i < 4; i++) m2[i] = fmaxf(s0[i], s1[i]);
#pragma unroll
    for (int msk = 1; msk <= 8; msk <<= 1)
#pragma unroll
      for (int i = 0; i < 4; i++) m2[i] = fmaxf(m2[i], __shfl_xor(m2[i], msk, 64));
    bool grew = (m2[0] > m_[0] + THRM) | (m2[1] > m_[1] + THRM) |
                (m2[2] > m_[2] + THRM) | (m2[3] > m_[3] + THRM);
    if (__any(grew)) {
#pragma unroll
      for (int i = 0; i < 4; i++) {
        float mn = fmaxf(m_[i], m2[i]);
        float al = exp2f((m_[i] - mn) * CS);
        m_[i] = mn;
        l_[i] *= al;
#pragma unroll
        for (int f = 0; f < 16; f++) o[f][i] *= al;
      }
    }
    // ---- P -> LDS (native bf16 cvt), read back as A-frag ----
#pragma unroll
    for (int i = 0; i < 4; i++) {
      const int row = 4 * g + i;
      const unsigned swz = (unsigned)(i << 4);
      float p0 = exp2f((s0[i] - m_[i]) * CS);
      float p1 = exp2f((s1[i] - m_[i]) * CS);
      l_[i] += p0 + p1;
      char* base = Ps[w] + row * 64;
      *(__bf16*)(base + ((unsigned)(c * 2) ^ swz)) = (__bf16)p0;
      *(__bf16*)(base + ((unsigned)(32 + c * 2) ^ swz)) = (__bf16)p1;
    }
    asm volatile("" ::: "memory");
    bf16x8 pa = *(const bf16x8*)(Ps[w] + c * 64 +
                 (((unsigned)(g * 16)) ^ ((unsigned)(c & 3) << 4)));
    // ---- O += P @ V ----
    const char* vread = KTs[cur] + g * 256 + c * 16;
#pragma unroll
    for (int f = 0; f < 16; f++) {
      bf16x8 vb = *(const bf16x8*)(vread + f * 1024);
      o[f] = MFMA(pa, vb, o[f]);
    }
  }
#undef STAGE

#pragma unroll
  for (int msk = 1; msk <= 8; msk <<= 1)
#pragma unroll
    for (int i = 0; i < 4; i++) l_[i] += __shfl_xor(l_[i], msk, 64);

  if (ksplit) {
    float* op = out + qrow0 * DD;
#pragma unroll
    for (int f = 0; f < 16; f++)
#pragma unroll
      for (int i = 0; i < 4; i++)
        op[(w * 16 + g * 4 + i) * DD + f * 16 + c] = o[f][i];
  } else {
    unsigned short* op = Op0 + qrow0 * DD;
#pragma unroll
    for (int f = 0; f < 16; f++)
#pragma unroll
      for (int i = 0; i < 4; i++)
        op[(w * 16 + g * 4 + i) * DD + f * 16 + c] = f2bf(o[f][i]);
  }
  if (c == 0) {
    float* mlp = ML + (qg * 2 + ksplit) * 128;
#pragma unroll
    for (int i = 0; i < 4; i++) {
      mlp[w * 16 + g * 4 + i] = m_[i];
      mlp[64 + w * 16 + g * 4 + i] = l_[i];
    }
  }
}

// ---------- merge the two key-split partials + residual ----------
__global__ __launch_bounds__(256) void merge_kernel(
    const unsigned short* __restrict__ Op0, const float* __restrict__ ML,
    const unsigned short* __restrict__ Qb, float* __restrict__ out) {
  const float CS = 0.03125f * 1.4426950408889634f;
  const long gid = (long)blockIdx.x * 256 + threadIdx.x;
  const long idx = gid * 8;
  const int row = (int)(idx >> 8);
  const int qg = row >> 6, qr = row & 63;
  const float m0 = ML[(qg * 2) * 128 + qr], l0 = ML[(qg * 2) * 128 + 64 + qr];
  const float m1 = ML[(qg * 2 + 1) * 128 + qr], l1 = ML[(qg * 2 + 1) * 128 + 64 + qr];
  const float M = fmaxf(m0, m1);
  const float e0 = exp2f((m0 - M) * CS), e1 = exp2f((m1 - M) * CS);
  const float inv = 1.0f / (e0 * l0 + e1 * l1);
  u16x8 p0 = *(const u16x8*)(Op0 + idx);
  f32x4 p1a = *(const f32x4*)(out + idx);
  f32x4 p1b = *(const f32x4*)(out + idx + 4);
  u16x8 qv = *(const u16x8*)(Qb + idx);
  f32x4 ra, rb;
#pragma unroll
  for (int e = 0; e < 4; e++)
    ra[e] = (e0 * bf2f(p0[e]) + e1 * p1a[e]) * inv + bf2f(qv[e]);
#pragma unroll
  for (int e = 0; e < 4; e++)
    rb[e] = (e0 * bf2f(p0[4 + e]) + e1 * p1b[e]) * inv + bf2f(qv[4 + e]);
  *(f32x4*)(out + idx) = ra;
  *(f32x4*)(out + idx + 4) = rb;
}

extern "C" void kernel_launch(void* const* d_in, const int* in_sizes, int n_in,
                              void* d_out, int out_size, void* d_ws, size_t ws_size,
                              hipStream_t stream) {
  (void)in_sizes; (void)n_in; (void)out_size; (void)ws_size;
  const float* data1 = (const float*)d_in[0];  // [8,2048,1024]
  const float* data2 = (const float*)d_in[1];  // [8,2048,256]
  const float* Wq = (const float*)d_in[2];     // [1024,256]
  const float* bq = (const float*)d_in[3];     // [256]
  const float* Wk = (const float*)d_in[4];     // [256,256]
  const float* bk = (const float*)d_in[5];     // [256]
  float* out = (float*)d_out;                  // [8,2048,256] f32

  char* ws = (char*)d_ws;
  unsigned short* Qb  = (unsigned short*)(ws);                        // 8 MB
  unsigned short* Kb  = (unsigned short*)(ws + (8ull << 20));         // 8 MB
  unsigned short* KTb = (unsigned short*)(ws + (16ull << 20));        // 8 MB
  unsigned short* WqT = (unsigned short*)(ws + (24ull << 20));        // 512 KB
  unsigned short* WkT = (unsigned short*)(ws + (24ull << 20) + (512u << 10));  // 128 KB
  unsigned short* Op0 = (unsigned short*)(ws + (25ull << 20));        // 8 MB
  float*          MLb = (float*)(ws + (33ull << 20));                 // 256 KB

  wt_kernel<<<dim3(1024), dim3(256), 0, stream>>>(Wq, WqT, 10, 256);
  wt_kernel<<<dim3(256), dim3(256), 0, stream>>>(Wk, WkT, 8, 256);
  proj_kernel<<<dim3(256), dim3(256), 0, stream>>>(data1, WqT, bq, Qb,
                                                   (unsigned short*)nullptr, 1024);
  proj_kernel<<<dim3(256), dim3(256), 0, stream>>>(data2, WkT, bk, Kb, KTb, 256);
  attn_kernel<<<dim3(512), dim3(256), 0, stream>>>(Qb, Kb, KTb, Op0, out, MLb);
  merge_kernel<<<dim3(2048), dim3(256), 0, stream>>>(Op0, MLb, Qb, out);
}